// Round 8
// baseline (305.754 us; speedup 1.0000x reference)
//
#include <hip/hip_runtime.h>

// Problem constants (from reference): B=128, NU=NI=5000, E=128, UF=IF=16, D=288
#define PB 128
#define PNU 5000
#define PE 128
#define PUF 16
#define PD 288            // 2*E + UF + IF

constexpr long MEM_ELEMS = (long)PB * PNU * PE;   // 81,920,000 floats per memory
constexpr int  OUT_HEAD  = PB * 2 * PE;           // 32,768 floats (out tensor)
constexpr long N4        = MEM_ELEMS / 4;         // 20,480,000 float4 per memory
constexpr int  GRU_BLOCKS  = PB;                  // 128 blocks: batch b, both sides
constexpr int  COPY_BLOCKS = 4096;                // total copy blocks
constexpr int  HALF_COPY   = COPY_BLOCKS / 2;     // 2048 per memory
// Weakly-positive cached-read window from R6 (kept; orthogonal).
constexpr long CACHED_N4 = 192L * 1024 * 1024 / 16;

typedef float f32x4 __attribute__((ext_vector_type(4)));

// ---------------------------------------------------------------------------
// Single fused dispatch.
//  blocks [0,128):        GRU for batch b (threads 0-127 user, 128-255 item).
//  blocks [128,2176):     copy user_memory  (ONE src + ONE dst stream/wave)
//  blocks [2176,4224):    copy item_memory  (ONE src + ONE dst stream/wave)
// Copy skips the 256 rows the GRU blocks write -> disjoint write sets, no
// ordering needed, deterministic. Single-stream-per-wave tests whether the
// 2src+2dst interleave was what capped BW at ~5.16 TB/s.
// ---------------------------------------------------------------------------
__global__ __launch_bounds__(256) void limnet_fused_kernel(
    const int* __restrict__ user_ids, const int* __restrict__ item_ids,
    const float* __restrict__ user_feat, const float* __restrict__ item_feat,
    const float* __restrict__ um_in, const float* __restrict__ im_in,
    const float* __restrict__ Wu, const float* __restrict__ bihu, const float* __restrict__ bhhu,
    const float* __restrict__ Wi, const float* __restrict__ bihi, const float* __restrict__ bhhi,
    float* __restrict__ out, float* __restrict__ um_out, float* __restrict__ im_out) {

  if (blockIdx.x >= (unsigned)GRU_BLOCKS) {
    // ---------------- copy path ----------------
    const int  cb     = blockIdx.x - GRU_BLOCKS;        // 0..4095
    const bool second = cb >= HALF_COPY;                // false: um, true: im
    const f32x4* __restrict__ src =
        second ? (const f32x4*)im_in : (const f32x4*)um_in;
    f32x4* __restrict__ dst = second ? (f32x4*)im_out : (f32x4*)um_out;
    const int* __restrict__ ids = second ? item_ids : user_ids;

    long i = (long)(second ? cb - HALF_COPY : cb) * 256 + threadIdx.x;
    const long stride = (long)HALF_COPY * 256;
    for (; i < N4; i += stride) {
      const int g = (int)(i >> 5);              // row index (32 f32x4 per row)
      const int b = g / PNU;                    // magic-mul, const divisor
      const int r = g - b * PNU;
      f32x4 a;
      if (!second && i < CACHED_N4) a = src[i];                        // allocating
      else                          a = __builtin_nontemporal_load(&src[i]);
      if (r != ids[b]) __builtin_nontemporal_store(a, &dst[i]);
    }
    return;
  }

  // ---------------- GRU path ----------------
  const int b    = blockIdx.x;
  const int t    = threadIdx.x;   // 0..255
  const int side = t >> 7;        // 0 = user update, 1 = item update
  const int l    = t & 127;       // output element within side

  __shared__ float xu[PD], xi[PD];
  __shared__ float wsum[4];

  const int uid = user_ids[b];
  const int iid = item_ids[b];
  const float* umrow = um_in + ((long)b * PNU + uid) * PE;
  const float* imrow = im_in + ((long)b * PNU + iid) * PE;

  // Build both concatenated input vectors in LDS:
  // xu = [um, uf, im, if], xi = [im, if, um, uf].
  if (side == 0) {
    const float v = umrow[l];
    xu[l] = v;
    xi[PE + PUF + l] = v;
    if (l < PUF) {
      const float f = user_feat[b * PUF + l];
      xu[PE + l]           = f;
      xi[2 * PE + PUF + l] = f;
    }
  } else {
    const float v = imrow[l];
    xi[l] = v;
    xu[PE + PUF + l] = v;
    if (l < PUF) {
      const float f = item_feat[b * PUF + l];
      xi[PE + l]           = f;
      xu[2 * PE + PUF + l] = f;
    }
  }
  __syncthreads();

  const float* W   = side ? Wi   : Wu;
  const float* bih = side ? bihi : bihu;
  const float* bhh = side ? bhhi : bhhu;
  const float* x   = side ? xi   : xu;

  // Rows are 288 floats = 1152 B, 16B-aligned -> float4 loads are valid.
  const float4* x4  = reinterpret_cast<const float4*>(x);
  const float4* wr4 = reinterpret_cast<const float4*>(W + (long)l * PD);
  const float4* wz4 = reinterpret_cast<const float4*>(W + (long)(PE + l) * PD);
  const float4* wn4 = reinterpret_cast<const float4*>(W + (long)(2 * PE + l) * PD);

  float ar = 0.f, az = 0.f, an = 0.f;
#pragma unroll 8
  for (int k = 0; k < PD / 4; ++k) {
    const float4 xv = x4[k];
    const float4 a = wr4[k];
    ar += a.x * xv.x + a.y * xv.y + a.z * xv.z + a.w * xv.w;
    const float4 c = wz4[k];
    az += c.x * xv.x + c.y * xv.y + c.z * xv.z + c.w * xv.w;
    const float4 e = wn4[k];
    an += e.x * xv.x + e.y * xv.y + e.z * xv.z + e.w * xv.w;
  }

  // GRUCell with h = 0 (gate order r, z, n):
  const float r = 1.f / (1.f + expf(-(ar + bih[l] + bhh[l])));
  const float z = 1.f / (1.f + expf(-(az + bih[PE + l] + bhh[PE + l])));
  const float n = tanhf(an + bih[2 * PE + l] + r * bhh[2 * PE + l]);
  const float h = (1.f - z) * n;

  // Per-side L2 norm: wave-64 shuffle reduce (waves 0,1 = user; 2,3 = item).
  float s = h * h;
  for (int off = 32; off; off >>= 1) s += __shfl_down(s, off, 64);
  if ((t & 63) == 0) wsum[t >> 6] = s;
  __syncthreads();
  const float inv = 1.f / fmaxf(sqrtf(wsum[side * 2] + wsum[side * 2 + 1]), 1e-12f);
  const float hn = h * inv;

  // out[b] = concat(u_new, i_new)
  out[(long)b * (2 * PE) + side * PE + l] = hn;

  // Write the updated rows (copy path skips exactly these).
  if (side == 0) um_out[((long)b * PNU + uid) * PE + l] = hn;
  else           im_out[((long)b * PNU + iid) * PE + l] = hn;
}

extern "C" void kernel_launch(void* const* d_in, const int* in_sizes, int n_in,
                              void* d_out, int out_size, void* d_ws, size_t ws_size,
                              hipStream_t stream) {
  const int*   user_ids  = (const int*)d_in[0];
  const int*   item_ids  = (const int*)d_in[1];
  const float* user_feat = (const float*)d_in[2];
  const float* item_feat = (const float*)d_in[3];
  const float* um        = (const float*)d_in[4];
  const float* im        = (const float*)d_in[5];
  const float* Wu        = (const float*)d_in[6];
  const float* bihu      = (const float*)d_in[7];
  const float* bhhu      = (const float*)d_in[8];
  const float* Wi        = (const float*)d_in[9];
  const float* bihi      = (const float*)d_in[10];
  const float* bhhi      = (const float*)d_in[11];

  float* out    = (float*)d_out;
  float* um_out = out + OUT_HEAD;          // 16B-aligned (32768*4 bytes)
  float* im_out = um_out + MEM_ELEMS;      // 16B-aligned

  limnet_fused_kernel<<<GRU_BLOCKS + COPY_BLOCKS, 256, 0, stream>>>(
      user_ids, item_ids, user_feat, item_feat, um, im,
      Wu, bihu, bhhu, Wi, bihi, bhhi, out, um_out, im_out);
}

// Round 9
// 251.630 us; speedup vs baseline: 1.2151x; 1.2151x over previous
//
#include <hip/hip_runtime.h>

// Problem constants (from reference): B=128, NU=NI=5000, E=128, UF=IF=16, D=288
#define PB 128
#define PNU 5000
#define PE 128
#define PUF 16
#define PD 288            // 2*E + UF + IF

constexpr long MEM_ELEMS = (long)PB * PNU * PE;   // 81,920,000 floats per memory
constexpr int  OUT_HEAD  = PB * 2 * PE;           // 32,768 floats (out tensor)
constexpr long N4        = MEM_ELEMS / 4;         // 20,480,000 float4 per memory
constexpr int  GRU_BLOCKS  = PB;                  // 128 blocks: batch b, both sides
constexpr int  COPY_BLOCKS = 4096;                // proven copy config (R1/R4/R6)
// Cached-read window (R6, +1%): these lines allocate in the 256 MiB MALL;
// everything else is NT. Kept as weakly positive.
constexpr long CACHED_N4 = 192L * 1024 * 1024 / 16;   // 12,582,912 f32x4

typedef float f32x4 __attribute__((ext_vector_type(4)));

// ---------------------------------------------------------------------------
// Single fused dispatch (best configuration, R6 = 254.2 us):
//  blocks [0,128):    GRU for batch b (threads 0-127 user side, 128-255 item).
//                     Reads ONLY input tensors -> safe concurrent with copy.
//  blocks [128,4224): interleaved 2-stream grid-stride NT copy of both
//                     memories, skipping the 256 rows the GRU blocks write.
// Disjoint write sets -> no ordering needed; deterministic.
// Copy-shape search (R1..R7): interleaved 2-stream grid-stride is optimal;
// deep unroll, LDS-id staging, load batching, and per-stream block split all
// regress. Mixed r/w ceiling on this chip/context: ~5.16 TB/s.
// ---------------------------------------------------------------------------
__global__ __launch_bounds__(256) void limnet_fused_kernel(
    const int* __restrict__ user_ids, const int* __restrict__ item_ids,
    const float* __restrict__ user_feat, const float* __restrict__ item_feat,
    const float* __restrict__ um_in, const float* __restrict__ im_in,
    const float* __restrict__ Wu, const float* __restrict__ bihu, const float* __restrict__ bhhu,
    const float* __restrict__ Wi, const float* __restrict__ bihi, const float* __restrict__ bhhi,
    float* __restrict__ out, float* __restrict__ um_out, float* __restrict__ im_out) {

  if (blockIdx.x >= (unsigned)GRU_BLOCKS) {
    // ---------------- copy path ----------------
    const f32x4* __restrict__ um4 = (const f32x4*)um_in;
    const f32x4* __restrict__ im4 = (const f32x4*)im_in;
    f32x4* __restrict__ oum4 = (f32x4*)um_out;
    f32x4* __restrict__ oim4 = (f32x4*)im_out;
    long i = (long)(blockIdx.x - GRU_BLOCKS) * 256 + threadIdx.x;
    const long stride = (long)COPY_BLOCKS * 256;
    for (; i < N4; i += stride) {
      const int g = (int)(i >> 5);              // row index (128 floats = 32 f32x4)
      const int b = g / PNU;                    // magic-mul, const divisor
      const int r = g - b * PNU;
      f32x4 a;
      if (i < CACHED_N4) a = um4[i];            // allocating load -> stays in MALL
      else               a = __builtin_nontemporal_load(&um4[i]);
      const f32x4 c = __builtin_nontemporal_load(&im4[i]);
      if (r != user_ids[b]) __builtin_nontemporal_store(a, &oum4[i]);
      if (r != item_ids[b]) __builtin_nontemporal_store(c, &oim4[i]);
    }
    return;
  }

  // ---------------- GRU path ----------------
  const int b    = blockIdx.x;
  const int t    = threadIdx.x;   // 0..255
  const int side = t >> 7;        // 0 = user update, 1 = item update
  const int l    = t & 127;       // output element within side

  __shared__ float xu[PD], xi[PD];
  __shared__ float wsum[4];

  const int uid = user_ids[b];
  const int iid = item_ids[b];
  const float* umrow = um_in + ((long)b * PNU + uid) * PE;
  const float* imrow = im_in + ((long)b * PNU + iid) * PE;

  // Build both concatenated input vectors in LDS:
  // xu = [um, uf, im, if], xi = [im, if, um, uf].
  if (side == 0) {
    const float v = umrow[l];
    xu[l] = v;
    xi[PE + PUF + l] = v;
    if (l < PUF) {
      const float f = user_feat[b * PUF + l];
      xu[PE + l]           = f;
      xi[2 * PE + PUF + l] = f;
    }
  } else {
    const float v = imrow[l];
    xi[l] = v;
    xu[PE + PUF + l] = v;
    if (l < PUF) {
      const float f = item_feat[b * PUF + l];
      xi[PE + l]           = f;
      xu[2 * PE + PUF + l] = f;
    }
  }
  __syncthreads();

  const float* W   = side ? Wi   : Wu;
  const float* bih = side ? bihi : bihu;
  const float* bhh = side ? bhhi : bhhu;
  const float* x   = side ? xi   : xu;

  // Rows are 288 floats = 1152 B, 16B-aligned -> float4 loads are valid.
  const float4* x4  = reinterpret_cast<const float4*>(x);
  const float4* wr4 = reinterpret_cast<const float4*>(W + (long)l * PD);
  const float4* wz4 = reinterpret_cast<const float4*>(W + (long)(PE + l) * PD);
  const float4* wn4 = reinterpret_cast<const float4*>(W + (long)(2 * PE + l) * PD);

  float ar = 0.f, az = 0.f, an = 0.f;
#pragma unroll 8
  for (int k = 0; k < PD / 4; ++k) {
    const float4 xv = x4[k];
    const float4 a = wr4[k];
    ar += a.x * xv.x + a.y * xv.y + a.z * xv.z + a.w * xv.w;
    const float4 c = wz4[k];
    az += c.x * xv.x + c.y * xv.y + c.z * xv.z + c.w * xv.w;
    const float4 e = wn4[k];
    an += e.x * xv.x + e.y * xv.y + e.z * xv.z + e.w * xv.w;
  }

  // GRUCell with h = 0 (gate order r, z, n):
  const float r = 1.f / (1.f + expf(-(ar + bih[l] + bhh[l])));
  const float z = 1.f / (1.f + expf(-(az + bih[PE + l] + bhh[PE + l])));
  const float n = tanhf(an + bih[2 * PE + l] + r * bhh[2 * PE + l]);
  const float h = (1.f - z) * n;

  // Per-side L2 norm: wave-64 shuffle reduce (waves 0,1 = user; 2,3 = item).
  float s = h * h;
  for (int off = 32; off; off >>= 1) s += __shfl_down(s, off, 64);
  if ((t & 63) == 0) wsum[t >> 6] = s;
  __syncthreads();
  const float inv = 1.f / fmaxf(sqrtf(wsum[side * 2] + wsum[side * 2 + 1]), 1e-12f);
  const float hn = h * inv;

  // out[b] = concat(u_new, i_new)
  out[(long)b * (2 * PE) + side * PE + l] = hn;

  // Write the updated rows (copy path skips exactly these).
  if (side == 0) um_out[((long)b * PNU + uid) * PE + l] = hn;
  else           im_out[((long)b * PNU + iid) * PE + l] = hn;
}

extern "C" void kernel_launch(void* const* d_in, const int* in_sizes, int n_in,
                              void* d_out, int out_size, void* d_ws, size_t ws_size,
                              hipStream_t stream) {
  const int*   user_ids  = (const int*)d_in[0];
  const int*   item_ids  = (const int*)d_in[1];
  const float* user_feat = (const float*)d_in[2];
  const float* item_feat = (const float*)d_in[3];
  const float* um        = (const float*)d_in[4];
  const float* im        = (const float*)d_in[5];
  const float* Wu        = (const float*)d_in[6];
  const float* bihu      = (const float*)d_in[7];
  const float* bhhu      = (const float*)d_in[8];
  const float* Wi        = (const float*)d_in[9];
  const float* bihi      = (const float*)d_in[10];
  const float* bhhi      = (const float*)d_in[11];

  float* out    = (float*)d_out;
  float* um_out = out + OUT_HEAD;          // 16B-aligned (32768*4 bytes)
  float* im_out = um_out + MEM_ELEMS;      // 16B-aligned

  limnet_fused_kernel<<<GRU_BLOCKS + COPY_BLOCKS, 256, 0, stream>>>(
      user_ids, item_ids, user_feat, item_feat, um, im,
      Wu, bihu, bhhu, Wi, bihi, bhhi, out, um_out, im_out);
}